// Round 1
// baseline (371.151 us; speedup 1.0000x reference)
//
#include <hip/hip_runtime.h>
#include <math.h>

#define C_ 512
#define H_ 128
#define W_ 128
#define B_ 4
#define K_ 19
#define M_ 5
#define P_ 95
#define P2 96
#define TPX 32
#define NBLK ((B_ * H_ * W_) / TPX)
#define HL2PI 470.49652900081467f  // 0.5 * 512 * ln(2*pi)

__device__ __forceinline__ float block_reduce_sum(float v, volatile float* red) {
#pragma unroll
  for (int o = 32; o; o >>= 1) v += __shfl_down(v, o);
  const int lane = threadIdx.x & 63, wv = threadIdx.x >> 6;
  if (lane == 0) red[wv] = v;
  __syncthreads();
  float r = red[0] + red[1] + red[2] + red[3];
  __syncthreads();
  return r;
}

// One block per prototype p (P2=96 blocks, last is zero-pad).
// Writes wpk[c*P2+p] = (inv_var, mu*inv_var) and cterm[p] = -0.5*q3 - logdet - HL2PI.
__global__ __launch_bounds__(256) void prep_kernel(
    const float* __restrict__ means, const float* __restrict__ diag,
    float2* __restrict__ wpk, float* __restrict__ cterm) {
  const int p = blockIdx.x;
  const int tid = threadIdx.x;
  __shared__ float red[4];
  if (p >= P_) {  // padding column: zero weights, never read in epilogue
    for (int c = tid; c < C_; c += 256) wpk[c * P2 + p] = make_float2(0.f, 0.f);
    if (tid == 0) cterm[p] = 0.f;
    return;
  }
  const float* mrow = means + (size_t)p * C_;
  const float* srow = diag + (size_t)p * C_;
  float m0 = mrow[tid], m1 = mrow[tid + 256];
  float ss = block_reduce_sum(m0 * m0 + m1 * m1, red);
  float rden = 1.f / fmaxf(sqrtf(ss), 1e-12f);  // l2_normalize(means)
  float q3 = 0.f, ld = 0.f;
#pragma unroll
  for (int t = 0; t < 2; t++) {
    int c = tid + t * 256;
    float m = mrow[c], s = srow[c];
    float mu = m * rden;
    float iv = 1.f / (s * s);
    wpk[c * P2 + p] = make_float2(iv, mu * iv);
    q3 += mu * mu * iv;
    ld += logf(s);
  }
  q3 = block_reduce_sum(q3, red);
  ld = block_reduce_sum(ld, red);
  if (tid == 0) cterm[p] = -0.5f * q3 - ld - HL2PI;
}

// One block = 32 consecutive pixels of one (b,h) row.
__global__ __launch_bounds__(256) void main_kernel(
    const float* __restrict__ x,
    const float* __restrict__ fg, const float* __restrict__ fb,
    const float* __restrict__ mg, const float* __restrict__ mb,
    const float2* __restrict__ wpk, const float* __restrict__ cterm,
    float* __restrict__ out) {
  __shared__ float xs[C_ * TPX];  // 64 KiB: x tile, then v tile, then (aliased) lp/mpr
  __shared__ float red0[8 * TPX];
  __shared__ float red1[8 * TPX];
  __shared__ float meanA[TPX], rstdA[TPX], rnA[TPX], rn2A[TPX];
  __shared__ float mean2A[TPX], rstd2A[TPX];

  const int tid = threadIdx.x;
  const int n0 = blockIdx.x * TPX;
  const int b = n0 >> 14;      // / (H*W)
  const int rem = n0 & 16383;
  const int h = rem >> 7;      // / W
  const int w0 = rem & 127;
  const float* xbase = x + ((size_t)(b * C_) * H_ + h) * W_ + w0;

  // Phase 1: stage x tile (coalesced: 32 consecutive w per channel)
  for (int idx = tid; idx < C_ * TPX; idx += 256) {
    int c = idx >> 5, px = idx & 31;
    xs[c * TPX + px] = xbase[(size_t)c * (H_ * W_) + px];
  }
  __syncthreads();

  const int px = tid & 31, part = tid >> 5;  // 8 parts x 32 px

  // Phase 2: LN stats (mean, rstd) per pixel
  {
    float s = 0.f, q = 0.f;
#pragma unroll 4
    for (int i = 0; i < 64; i++) {
      float v = xs[(part * 64 + i) * TPX + px];
      s += v;
      q += v * v;
    }
    red0[part * TPX + px] = s;
    red1[part * TPX + px] = q;
  }
  __syncthreads();
  if (tid < TPX) {
    float ss = 0.f, qq = 0.f;
#pragma unroll
    for (int i = 0; i < 8; i++) {
      ss += red0[i * TPX + tid];
      qq += red1[i * TPX + tid];
    }
    float mean = ss * (1.f / C_);
    float var = qq * (1.f / C_) - mean * mean;
    meanA[tid] = mean;
    rstdA[tid] = rsqrtf(var + 1e-5f);
  }
  __syncthreads();

  // Phase 3: v = gamma*xhat + beta written back to LDS; accumulate ||v||^2
  {
    float mean = meanA[px], rstd = rstdA[px];
    float s2 = 0.f;
#pragma unroll 4
    for (int i = 0; i < 64; i++) {
      int c = part * 64 + i;
      float v = (xs[c * TPX + px] - mean) * rstd;
      v = fmaf(v, fg[c], fb[c]);
      s2 += v * v;
      xs[c * TPX + px] = v;
    }
    red0[part * TPX + px] = s2;
  }
  __syncthreads();
  if (tid < TPX) {
    float ss = 0.f;
#pragma unroll
    for (int i = 0; i < 8; i++) ss += red0[i * TPX + tid];
    float rn = 1.f / fmaxf(sqrtf(ss), 1e-12f);  // l2_normalize folded into epilogue
    rnA[tid] = rn;
    rn2A[tid] = rn * rn;
  }
  __syncthreads();

  // Phase 4: a1[p][px] = sum_c v^2*iv, a2[p][px] = sum_c v*(mu*iv)
  // thread tile: 3 prototypes x 4 pixels
  const int pg = tid & 31;   // p group (p varies fastest across lanes -> coalesced w)
  const int pxg = tid >> 5;  // 8 pixel groups of 4 (half-wave broadcast LDS read)
  const int pb = 3 * pg;
  float a1[3][4] = {}, a2[3][4] = {};
  const float* vptr = xs + pxg * 4;
#pragma unroll 2
  for (int c = 0; c < C_; c++) {
    const float4 v4 = *(const float4*)(vptr + c * TPX);
    const float2* wrow = wpk + c * P2 + pb;
    const float2 wa = wrow[0], wb = wrow[1], wc = wrow[2];
    const float vv[4] = {v4.x, v4.y, v4.z, v4.w};
#pragma unroll
    for (int i = 0; i < 4; i++) {
      float v = vv[i], v2 = v * v;
      a1[0][i] = fmaf(v2, wa.x, a1[0][i]);
      a2[0][i] = fmaf(v, wa.y, a2[0][i]);
      a1[1][i] = fmaf(v2, wb.x, a1[1][i]);
      a2[1][i] = fmaf(v, wb.y, a2[1][i]);
      a1[2][i] = fmaf(v2, wc.x, a1[2][i]);
      a2[2][i] = fmaf(v, wc.y, a2[2][i]);
    }
  }
  __syncthreads();  // xs (v tile) dead from here; alias as lp
  float* lp = xs;          // [TPX][P2]
  float* mpr = xs + 8192;  // [TPX][20]
#pragma unroll
  for (int j = 0; j < 3; j++) {
    const int p = pb + j;
    const float ct = cterm[p];
#pragma unroll
    for (int i = 0; i < 4; i++) {
      const int pxx = pxg * 4 + i;
      // logp = -0.5*rn2*a1 + rn*a2 + (-0.5*q3 - logdet - HL2PI)
      lp[pxx * P2 + p] = fmaf(-0.5f * rn2A[pxx], a1[j][i], fmaf(rnA[pxx], a2[j][i], ct));
    }
  }
  __syncthreads();

  // Phase 5a: max over M components
  for (int idx = tid; idx < TPX * K_; idx += 256) {
    const int pxx = idx / K_;
    const int k = idx - pxx * K_;
    const float* row = lp + pxx * P2 + k * M_;
    float mv = row[0];
#pragma unroll
    for (int m = 1; m < M_; m++) mv = fmaxf(mv, row[m]);
    mpr[pxx * 20 + k] = mv;
  }
  __syncthreads();
  // Phase 5b: LN over K (two-pass! values ~ -470, var ~ 1e-3)
  if (tid < TPX) {
    float ss = 0.f;
    for (int k = 0; k < K_; k++) ss += mpr[tid * 20 + k];
    float m2 = ss * (1.f / K_);
    float qq = 0.f;
    for (int k = 0; k < K_; k++) {
      float d = mpr[tid * 20 + k] - m2;
      qq += d * d;
    }
    mean2A[tid] = m2;
    rstd2A[tid] = rsqrtf(qq * (1.f / K_) + 1e-5f);
  }
  __syncthreads();
  // Phase 5c: coalesced store to (B,K,H,W)
  float* obase = out + ((size_t)(b * K_) * H_ + h) * W_ + w0;
  for (int idx = tid; idx < TPX * K_; idx += 256) {
    const int k = idx >> 5, pxx = idx & 31;
    float v = fmaf((mpr[pxx * 20 + k] - mean2A[pxx]) * rstd2A[pxx], mg[k], mb[k]);
    obase[(size_t)k * (H_ * W_) + pxx] = v;
  }
}

extern "C" void kernel_launch(void* const* d_in, const int* in_sizes, int n_in,
                              void* d_out, int out_size, void* d_ws, size_t ws_size,
                              hipStream_t stream) {
  const float* x = (const float*)d_in[0];
  const float* means = (const float*)d_in[1];
  const float* diag = (const float*)d_in[2];
  const float* fg = (const float*)d_in[3];
  const float* fb = (const float*)d_in[4];
  const float* mg = (const float*)d_in[5];
  const float* mb = (const float*)d_in[6];
  float* out = (float*)d_out;

  float2* wpk = (float2*)d_ws;                                        // 512*96*8 B
  float* cterm = (float*)((char*)d_ws + (size_t)C_ * P2 * sizeof(float2));  // +96*4 B

  prep_kernel<<<P2, 256, 0, stream>>>(means, diag, wpk, cterm);
  main_kernel<<<NBLK, 256, 0, stream>>>(x, fg, fb, mg, mb, wpk, cterm, out);
}

// Round 2
// 81.446 us; speedup vs baseline: 4.5570x; 4.5570x over previous
//
#include <hip/hip_runtime.h>
#include <math.h>

#define C_ 512
#define HW_ 16384
#define K_ 19
#define M_ 5
#define P_ 95
#define P2 96
#define TPX 32
#define NBLK 2048
#define HL2PI 470.49652900081467f  // 0.5 * 512 * ln(2*pi)

typedef __attribute__((ext_vector_type(8))) short short8;
typedef __attribute__((ext_vector_type(4))) float float4v;

// fp32 -> bf16 RNE, returned as raw short
static __device__ __forceinline__ short f2bf(float f) {
  unsigned u = __builtin_bit_cast(unsigned, f);
  unsigned r = (u + 0x7fffu + ((u >> 16) & 1u)) >> 16;
  return (short)r;
}

__device__ __forceinline__ float block_reduce_sum(float v, volatile float* red) {
#pragma unroll
  for (int o = 32; o; o >>= 1) v += __shfl_down(v, o);
  const int lane = threadIdx.x & 63, wv = threadIdx.x >> 6;
  if (lane == 0) red[wv] = v;
  __syncthreads();
  float r = red[0] + red[1] + red[2] + red[3];
  __syncthreads();
  return r;
}

// One block per prototype p. wbf[p][k] bf16 row-major [96][1024]:
//   k <  512: inv_var[c]          (A-operand for the v^2 half)
//   k >= 512: mu[c]*inv_var[c]    (A-operand for the v half)
// cterm[p] = -0.5*q3 - logdet - HL2PI  (fp32)
__global__ __launch_bounds__(256) void prep_kernel(
    const float* __restrict__ means, const float* __restrict__ diag,
    short* __restrict__ wbf, float* __restrict__ cterm) {
  const int p = blockIdx.x;
  const int tid = threadIdx.x;
  __shared__ float red[4];
  if (p >= P_) {  // zero-pad row 95: contributes 0, never selected in max
    for (int c = tid; c < C_; c += 256) {
      wbf[p * 1024 + c] = 0;
      wbf[p * 1024 + 512 + c] = 0;
    }
    if (tid == 0) cterm[p] = 0.f;
    return;
  }
  const float* mrow = means + (size_t)p * C_;
  const float* srow = diag + (size_t)p * C_;
  float m0 = mrow[tid], m1 = mrow[tid + 256];
  float ss = block_reduce_sum(m0 * m0 + m1 * m1, red);
  float rden = 1.f / fmaxf(sqrtf(ss), 1e-12f);  // l2_normalize(means)
  float q3 = 0.f, ld = 0.f;
#pragma unroll
  for (int t = 0; t < 2; t++) {
    int c = tid + t * 256;
    float m = mrow[c], s = srow[c];
    float mu = m * rden;
    float iv = 1.f / (s * s);
    wbf[p * 1024 + c] = f2bf(iv);
    wbf[p * 1024 + 512 + c] = f2bf(mu * iv);
    q3 += mu * mu * iv;
    ld += logf(s);
  }
  q3 = block_reduce_sum(q3, red);
  ld = block_reduce_sum(ld, red);
  if (tid == 0) cterm[p] = -0.5f * q3 - ld - HL2PI;
}

// One block = 32 pixels. 4 waves: wave = (khalf = wv>>1, phalf = wv&1).
// u LDS is fragment-native: block (t, ks) of 1KB holds, at byte l*16 + j*2,
// u[k = ks*32 + (l>>4)*8 + j][px = t*16 + (l&15)]  -> B-frag read = base + lane*16.
__global__ __launch_bounds__(256) void main_kernel(
    const float* __restrict__ x,
    const float* __restrict__ fg, const float* __restrict__ fb,
    const float* __restrict__ mg, const float* __restrict__ mb,
    const short* __restrict__ wbf, const float* __restrict__ cterm,
    float* __restrict__ out) {
  __shared__ __align__(16) char raw[65536];  // u (64 KiB), later aliased as lp[32][100]
  __shared__ float red0[8 * TPX], red1[8 * TPX];
  __shared__ float meanA[TPX], rstdA[TPX], rnA[TPX], rn2A[TPX];
  __shared__ float mean2A[TPX], rstd2A[TPX];
  __shared__ float mpr[TPX * 20];

  const int tid = threadIdx.x;
  const int px = tid & 31, part = tid >> 5;
  const int n0 = blockIdx.x * TPX;
  const int b = n0 >> 14;
  const int rem = n0 & 16383;
  const int h = rem >> 7;
  const int w0 = rem & 127;

  // ---- Pass 1: x -> registers (single HBM pass), LN stats ----
  const float* xp = x + (size_t)b * C_ * HW_ + h * 128 + w0 + px;
  const int cbase = part * 64;
  float xr[64];
#pragma unroll
  for (int i = 0; i < 64; i++) xr[i] = xp[(size_t)(cbase + i) * HW_];
  {
    float s = 0.f, q = 0.f;
#pragma unroll
    for (int i = 0; i < 64; i++) {
      s += xr[i];
      q += xr[i] * xr[i];
    }
    red0[part * 32 + px] = s;
    red1[part * 32 + px] = q;
  }
  __syncthreads();
  if (tid < 32) {
    float ss = 0.f, qq = 0.f;
#pragma unroll
    for (int i = 0; i < 8; i++) {
      ss += red0[i * 32 + tid];
      qq += red1[i * 32 + tid];
    }
    float mean = ss * (1.f / C_);
    float var = qq * (1.f / C_) - mean * mean;
    meanA[tid] = mean;
    rstdA[tid] = rsqrtf(var + 1e-5f);
  }
  __syncthreads();

  // ---- Pass 2: v = LN(x)*g+b (fp32), write u = [v^2 | v] bf16 to LDS, sum v^2 ----
  {
    const float mean = meanA[px], rstd = rstdA[px];
    float s2 = 0.f;
    const int t_ = px >> 4;
    const int lq = px & 15;
#pragma unroll
    for (int t8 = 0; t8 < 8; t8++) {
      const int c0 = cbase + t8 * 8;
      short8 v2p, vp;
#pragma unroll
      for (int j = 0; j < 8; j++) {
        const int c = c0 + j;
        float v = (xr[t8 * 8 + j] - mean) * rstd;
        v = fmaf(v, fg[c], fb[c]);
        s2 += v * v;
        v2p[j] = f2bf(v * v);
        vp[j] = f2bf(v);
      }
      const int l = (((c0 >> 3) & 3) << 4) | lq;
      const int ks1 = c0 >> 5;        // k = c      (v^2 half)
      const int ks2 = 16 + ks1;       // k = 512+c  (v half)
      *(short8*)(raw + (((t_ * 32 + ks1) << 10) | (l << 4))) = v2p;
      *(short8*)(raw + (((t_ * 32 + ks2) << 10) | (l << 4))) = vp;
    }
    red0[part * 32 + px] = s2;
  }
  __syncthreads();
  if (tid < 32) {
    float ss = 0.f;
#pragma unroll
    for (int i = 0; i < 8; i++) ss += red0[i * 32 + tid];
    float rn = 1.f / fmaxf(sqrtf(ss), 1e-12f);  // l2_normalize folded into epilogue
    rnA[tid] = rn;
    rn2A[tid] = rn * rn;
  }
  __syncthreads();

  // ---- MFMA: lp[p][px], split-K accumulators ----
  const int wv = tid >> 6, lane = tid & 63;
  const int pbase = (wv & 1) * 3;   // 3 p-tiles per wave
  const int khalf = wv >> 1;        // 0: a1 (v^2*iv), 1: a2 (v*mu*iv)
  const int lm = lane & 15, lk = lane >> 4;
  float4v acc[3][2] = {};
  const short* wrow = wbf + (((pbase * 16 + lm) << 10) | (khalf << 9) | (lk << 3));
#pragma unroll 4
  for (int ksl = 0; ksl < 16; ksl++) {
    const int ks = khalf * 16 + ksl;
    short8 a0 = *(const short8*)(wrow + ksl * 32);
    short8 a1 = *(const short8*)(wrow + 16384 + ksl * 32);  // +16 rows
    short8 a2 = *(const short8*)(wrow + 32768 + ksl * 32);
    short8 b0 = *(const short8*)(raw + ((ks << 10) | (lane << 4)));
    short8 b1 = *(const short8*)(raw + (((32 + ks) << 10) | (lane << 4)));
    acc[0][0] = __builtin_amdgcn_mfma_f32_16x16x32_bf16(a0, b0, acc[0][0], 0, 0, 0);
    acc[0][1] = __builtin_amdgcn_mfma_f32_16x16x32_bf16(a0, b1, acc[0][1], 0, 0, 0);
    acc[1][0] = __builtin_amdgcn_mfma_f32_16x16x32_bf16(a1, b0, acc[1][0], 0, 0, 0);
    acc[1][1] = __builtin_amdgcn_mfma_f32_16x16x32_bf16(a1, b1, acc[1][1], 0, 0, 0);
    acc[2][0] = __builtin_amdgcn_mfma_f32_16x16x32_bf16(a2, b0, acc[2][0], 0, 0, 0);
    acc[2][1] = __builtin_amdgcn_mfma_f32_16x16x32_bf16(a2, b1, acc[2][1], 0, 0, 0);
  }
  __syncthreads();  // u dead; alias raw as lp[32][100]
  float* lp = (float*)raw;

  // stage 1: a1 waves write -0.5*rn2*a1 + ct
  if (khalf == 0) {
#pragma unroll
    for (int i = 0; i < 3; i++) {
      const int prow = (pbase + i) * 16 + lk * 4;
#pragma unroll
      for (int r = 0; r < 4; r++) {
        const float ct = cterm[prow + r];
#pragma unroll
        for (int t = 0; t < 2; t++) {
          const int pxx = t * 16 + lm;
          lp[pxx * 100 + prow + r] = fmaf(-0.5f * rn2A[pxx], acc[i][t][r], ct);
        }
      }
    }
  }
  __syncthreads();
  // stage 2: a2 waves add rn*a2
  if (khalf == 1) {
#pragma unroll
    for (int i = 0; i < 3; i++) {
      const int prow = (pbase + i) * 16 + lk * 4;
#pragma unroll
      for (int r = 0; r < 4; r++) {
#pragma unroll
        for (int t = 0; t < 2; t++) {
          const int pxx = t * 16 + lm;
          lp[pxx * 100 + prow + r] += rnA[pxx] * acc[i][t][r];
        }
      }
    }
  }
  __syncthreads();

  // ---- max over M components ----
  for (int idx = tid; idx < TPX * K_; idx += 256) {
    const int pxx = idx / K_;
    const int k = idx - pxx * K_;
    const float* row = lp + pxx * 100 + k * M_;
    float mv = row[0];
#pragma unroll
    for (int m = 1; m < M_; m++) mv = fmaxf(mv, row[m]);
    mpr[pxx * 20 + k] = mv;
  }
  __syncthreads();
  // ---- LN over K (two-pass: values ~ -470, var ~ 1e-3) ----
  if (tid < 32) {
    float ss = 0.f;
    for (int k = 0; k < K_; k++) ss += mpr[tid * 20 + k];
    float m2 = ss * (1.f / K_);
    float qq = 0.f;
    for (int k = 0; k < K_; k++) {
      float d = mpr[tid * 20 + k] - m2;
      qq += d * d;
    }
    mean2A[tid] = m2;
    rstd2A[tid] = rsqrtf(qq * (1.f / K_) + 1e-5f);
  }
  __syncthreads();
  // ---- coalesced store (B,K,H,W) ----
  float* obase = out + ((size_t)(b * K_) * 128 + h) * 128 + w0;
  for (int idx = tid; idx < TPX * K_; idx += 256) {
    const int k = idx >> 5, pxx = idx & 31;
    float v = fmaf((mpr[pxx * 20 + k] - mean2A[pxx]) * rstd2A[pxx], mg[k], mb[k]);
    obase[(size_t)k * HW_ + pxx] = v;
  }
}

extern "C" void kernel_launch(void* const* d_in, const int* in_sizes, int n_in,
                              void* d_out, int out_size, void* d_ws, size_t ws_size,
                              hipStream_t stream) {
  const float* x = (const float*)d_in[0];
  const float* means = (const float*)d_in[1];
  const float* diag = (const float*)d_in[2];
  const float* fg = (const float*)d_in[3];
  const float* fb = (const float*)d_in[4];
  const float* mg = (const float*)d_in[5];
  const float* mb = (const float*)d_in[6];
  float* out = (float*)d_out;

  short* wbf = (short*)d_ws;                                   // 96*1024*2 B
  float* cterm = (float*)((char*)d_ws + (size_t)P2 * 1024 * 2);  // +96*4 B

  prep_kernel<<<P2, 256, 0, stream>>>(means, diag, wbf, cterm);
  main_kernel<<<NBLK, 256, 0, stream>>>(x, fg, fb, mg, mb, wbf, cterm, out);
}